// Round 1
// baseline (407.197 us; speedup 1.0000x reference)
//
#include <hip/hip_runtime.h>
#include <math.h>

// dims
#define B_   64
#define N1_  1152
#define P_   8
#define N2_  128
#define D_   16
#define ISPLIT 32
#define ICH  (N1_/ISPLIT)   // 36 i's per split

// ---------------------------------------------------------------------------
// K1: s0 partials.  s0p[split][b][n][d] = sum_{i in split, p} W[i,n,d,p]*x[b,i,p]
// block: 256 thr = (n 16) x (bgroup 8 -> 8 b each) x (dgroup 2 -> 8 d each)
// grid: (N2/16, ISPLIT) = (8, 32)
// ---------------------------------------------------------------------------
__global__ __launch_bounds__(256) void k1_s0(const float* __restrict__ x,
                                             const float* __restrict__ W,
                                             float* __restrict__ s0p)
{
    __shared__ float Wl[16 * 132];            // 16 n x (128 + 4 pad) floats
    const int tid = threadIdx.x;
    const int n0  = blockIdx.x * 16;
    const int isp = blockIdx.y;
    const int i0  = isp * ICH;
    const int nl  = tid & 15;
    const int bg  = (tid >> 4) & 7;
    const int dg  = tid >> 7;
    const int b0  = bg * 8, d0 = dg * 8;

    float acc[8][8];
#pragma unroll
    for (int a = 0; a < 8; ++a)
#pragma unroll
        for (int c = 0; c < 8; ++c) acc[a][c] = 0.f;

    for (int ii = 0; ii < ICH; ++ii) {
        const int i = i0 + ii;
        __syncthreads();
        // stage W[i, n0..n0+15, :, :] : 2048 contiguous floats -> padded LDS
        const float4* Wg = (const float4*)(W + ((size_t)i * N2_ + n0) * (D_ * P_));
        for (int t = tid; t < 512; t += 256) {
            float4 v = Wg[t];
            int nn = t >> 5, r = t & 31;
            *(float4*)&Wl[nn * 132 + r * 4] = v;
        }
        __syncthreads();

        float xr[8][8];
#pragma unroll
        for (int bb = 0; bb < 8; ++bb) {
            const float* xp = x + ((size_t)(b0 + bb) * N1_ + i) * P_;
            float4 a0 = *(const float4*)xp;
            float4 a1 = *(const float4*)(xp + 4);
            xr[bb][0] = a0.x; xr[bb][1] = a0.y; xr[bb][2] = a0.z; xr[bb][3] = a0.w;
            xr[bb][4] = a1.x; xr[bb][5] = a1.y; xr[bb][6] = a1.z; xr[bb][7] = a1.w;
        }
#pragma unroll
        for (int dd = 0; dd < 8; ++dd) {
            const float* wp = &Wl[nl * 132 + (d0 + dd) * P_];
            float4 w0 = *(const float4*)wp;
            float4 w1 = *(const float4*)(wp + 4);
#pragma unroll
            for (int bb = 0; bb < 8; ++bb) {
                float t = w0.x * xr[bb][0] + w0.y * xr[bb][1]
                        + w0.z * xr[bb][2] + w0.w * xr[bb][3]
                        + w1.x * xr[bb][4] + w1.y * xr[bb][5]
                        + w1.z * xr[bb][6] + w1.w * xr[bb][7];
                acc[bb][dd] += t;
            }
        }
    }
#pragma unroll
    for (int bb = 0; bb < 8; ++bb)
#pragma unroll
        for (int dd = 0; dd < 8; ++dd)
            s0p[(size_t)isp * (B_ * N2_ * D_) + (size_t)(b0 + bb) * (N2_ * D_)
                + (n0 + nl) * D_ + d0 + dd] = acc[bb][dd];
}

// ---------------------------------------------------------------------------
// K2/K4: reduce ISPLIT partials, scale, squash over d (16), write v.
// one thread per (b,n,d); 16-lane subgroups share a (b,n) row.
// ---------------------------------------------------------------------------
__global__ __launch_bounds__(256) void k2_squash(const float* __restrict__ spart,
                                                 float* __restrict__ vout,
                                                 float scale)
{
    int idx = blockIdx.x * 256 + threadIdx.x;   // 0 .. 131071
    float s = 0.f;
    for (int sp = 0; sp < ISPLIT; ++sp)
        s += spart[(size_t)sp * (B_ * N2_ * D_) + idx];
    s *= scale;
    float sq = s * s;
    sq += __shfl_xor(sq, 1);
    sq += __shfl_xor(sq, 2);
    sq += __shfl_xor(sq, 4);
    sq += __shfl_xor(sq, 8);
    float norm = sqrtf(sq + 1.1920929e-7f);
    vout[idx] = (sq / (1.f + sq)) * (s / norm);
}

// ---------------------------------------------------------------------------
// K3a: raw[b][i][n] = sum_d v0[b,n,d] * (sum_p W[i,n,d,p]*x[b,i,p])
// block: 256 thr = (n 8) x (bgroup 16 -> 4 b each) x (ii 2)
// grid: (N2/8, ISPLIT) = (16, 32).  v0 slice held in registers (indep of i).
// ---------------------------------------------------------------------------
__global__ __launch_bounds__(256) void k3a_raw(const float* __restrict__ x,
                                               const float* __restrict__ W,
                                               const float* __restrict__ v0,
                                               float* __restrict__ raw)
{
    __shared__ float Wl[2 * 8 * 132];           // [ii][n][128+4]
    const int tid = threadIdx.x;
    const int n0  = blockIdx.x * 8;
    const int i0  = blockIdx.y * ICH;
    const int nl  = tid & 7;
    const int bgi = (tid >> 3) & 15;
    const int ii  = tid >> 7;
    const int b0  = bgi * 4;

    float v0r[4][16];
#pragma unroll
    for (int bb = 0; bb < 4; ++bb) {
        const float4* vp = (const float4*)(v0 + (size_t)(b0 + bb) * (N2_ * D_)
                                           + (n0 + nl) * D_);
        float4 q0 = vp[0], q1 = vp[1], q2 = vp[2], q3 = vp[3];
        v0r[bb][0]  = q0.x; v0r[bb][1]  = q0.y; v0r[bb][2]  = q0.z; v0r[bb][3]  = q0.w;
        v0r[bb][4]  = q1.x; v0r[bb][5]  = q1.y; v0r[bb][6]  = q1.z; v0r[bb][7]  = q1.w;
        v0r[bb][8]  = q2.x; v0r[bb][9]  = q2.y; v0r[bb][10] = q2.z; v0r[bb][11] = q2.w;
        v0r[bb][12] = q3.x; v0r[bb][13] = q3.y; v0r[bb][14] = q3.z; v0r[bb][15] = q3.w;
    }

    for (int s = 0; s < ICH / 2; ++s) {
        __syncthreads();
        for (int t = tid; t < 512; t += 256) {
            int iw = t >> 8, rem = t & 255;
            int nn = rem >> 5, r = rem & 31;
            float4 v = *(const float4*)(W + ((size_t)(i0 + 2 * s + iw) * N2_ + n0 + nn)
                                            * (D_ * P_) + r * 4);
            *(float4*)&Wl[(iw * 8 + nn) * 132 + r * 4] = v;
        }
        __syncthreads();

        const int i = i0 + 2 * s + ii;
        float xr[4][8];
#pragma unroll
        for (int bb = 0; bb < 4; ++bb) {
            const float* xp = x + ((size_t)(b0 + bb) * N1_ + i) * P_;
            float4 a0 = *(const float4*)xp;
            float4 a1 = *(const float4*)(xp + 4);
            xr[bb][0] = a0.x; xr[bb][1] = a0.y; xr[bb][2] = a0.z; xr[bb][3] = a0.w;
            xr[bb][4] = a1.x; xr[bb][5] = a1.y; xr[bb][6] = a1.z; xr[bb][7] = a1.w;
        }
        float rawp[4] = {0.f, 0.f, 0.f, 0.f};
#pragma unroll
        for (int d = 0; d < 16; ++d) {
            const float* wp = &Wl[(ii * 8 + nl) * 132 + d * P_];
            float4 w0 = *(const float4*)wp;
            float4 w1 = *(const float4*)(wp + 4);
#pragma unroll
            for (int bb = 0; bb < 4; ++bb) {
                float t = w0.x * xr[bb][0] + w0.y * xr[bb][1]
                        + w0.z * xr[bb][2] + w0.w * xr[bb][3]
                        + w1.x * xr[bb][4] + w1.y * xr[bb][5]
                        + w1.z * xr[bb][6] + w1.w * xr[bb][7];
                rawp[bb] += t * v0r[bb][d];
            }
        }
#pragma unroll
        for (int bb = 0; bb < 4; ++bb)
            raw[(size_t)(b0 + bb) * (N1_ * N2_) + (size_t)i * N2_ + n0 + nl] = rawp[bb];
    }
}

// ---------------------------------------------------------------------------
// K3b: in-place softmax over n (128) per (b,i) row. one wave per row.
// ---------------------------------------------------------------------------
__global__ __launch_bounds__(256) void k3b_softmax(float* __restrict__ raw)
{
    int row  = blockIdx.x * 4 + (threadIdx.x >> 6);   // 0 .. 73727
    int lane = threadIdx.x & 63;
    float* rp = raw + (size_t)row * N2_;
    float a = rp[lane], b = rp[lane + 64];
    float m = fmaxf(a, b);
#pragma unroll
    for (int off = 32; off >= 1; off >>= 1) m = fmaxf(m, __shfl_xor(m, off));
    float e0 = __expf(a - m), e1 = __expf(b - m);
    float ssum = e0 + e1;
#pragma unroll
    for (int off = 32; off >= 1; off >>= 1) ssum += __shfl_xor(ssum, off);
    float inv = 1.f / ssum;
    rp[lane] = e0 * inv;
    rp[lane + 64] = e1 * inv;
}

// ---------------------------------------------------------------------------
// K3c: s1 partials.  s1p[split][b][n][d] = sum_{i in split} c[b,i,n]*pred[b,i,n,d]
// identical blocking to K1 plus the c weight.
// ---------------------------------------------------------------------------
__global__ __launch_bounds__(256) void k3c_s1(const float* __restrict__ x,
                                              const float* __restrict__ W,
                                              const float* __restrict__ cmat,
                                              float* __restrict__ s1p)
{
    __shared__ float Wl[16 * 132];
    const int tid = threadIdx.x;
    const int n0  = blockIdx.x * 16;
    const int isp = blockIdx.y;
    const int i0  = isp * ICH;
    const int nl  = tid & 15;
    const int bg  = (tid >> 4) & 7;
    const int dg  = tid >> 7;
    const int b0  = bg * 8, d0 = dg * 8;

    float acc[8][8];
#pragma unroll
    for (int a = 0; a < 8; ++a)
#pragma unroll
        for (int c = 0; c < 8; ++c) acc[a][c] = 0.f;

    for (int ii = 0; ii < ICH; ++ii) {
        const int i = i0 + ii;
        __syncthreads();
        const float4* Wg = (const float4*)(W + ((size_t)i * N2_ + n0) * (D_ * P_));
        for (int t = tid; t < 512; t += 256) {
            float4 v = Wg[t];
            int nn = t >> 5, r = t & 31;
            *(float4*)&Wl[nn * 132 + r * 4] = v;
        }
        __syncthreads();

        float xr[8][8];
        float cr[8];
#pragma unroll
        for (int bb = 0; bb < 8; ++bb) {
            const float* xp = x + ((size_t)(b0 + bb) * N1_ + i) * P_;
            float4 a0 = *(const float4*)xp;
            float4 a1 = *(const float4*)(xp + 4);
            xr[bb][0] = a0.x; xr[bb][1] = a0.y; xr[bb][2] = a0.z; xr[bb][3] = a0.w;
            xr[bb][4] = a1.x; xr[bb][5] = a1.y; xr[bb][6] = a1.z; xr[bb][7] = a1.w;
            cr[bb] = cmat[(size_t)(b0 + bb) * (N1_ * N2_) + (size_t)i * N2_ + n0 + nl];
        }
#pragma unroll
        for (int dd = 0; dd < 8; ++dd) {
            const float* wp = &Wl[nl * 132 + (d0 + dd) * P_];
            float4 w0 = *(const float4*)wp;
            float4 w1 = *(const float4*)(wp + 4);
#pragma unroll
            for (int bb = 0; bb < 8; ++bb) {
                float t = w0.x * xr[bb][0] + w0.y * xr[bb][1]
                        + w0.z * xr[bb][2] + w0.w * xr[bb][3]
                        + w1.x * xr[bb][4] + w1.y * xr[bb][5]
                        + w1.z * xr[bb][6] + w1.w * xr[bb][7];
                acc[bb][dd] += cr[bb] * t;
            }
        }
    }
#pragma unroll
    for (int bb = 0; bb < 8; ++bb)
#pragma unroll
        for (int dd = 0; dd < 8; ++dd)
            s1p[(size_t)isp * (B_ * N2_ * D_) + (size_t)(b0 + bb) * (N2_ * D_)
                + (n0 + nl) * D_ + d0 + dd] = acc[bb][dd];
}

// ---------------------------------------------------------------------------
extern "C" void kernel_launch(void* const* d_in, const int* in_sizes, int n_in,
                              void* d_out, int out_size, void* d_ws, size_t ws_size,
                              hipStream_t stream)
{
    const float* x = (const float*)d_in[0];   // [64,1152,8]
    const float* W = (const float*)d_in[1];   // [1152,128,16,8]
    float* out = (float*)d_out;               // [64,128,16]

    // workspace layout (all written before read; no reliance on init)
    float* s_part = (float*)d_ws;                              // 32*131072 floats (16 MB), reused for s0p then s1p
    float* v0     = s_part + (size_t)ISPLIT * B_ * N2_ * D_;   // 131072 floats
    float* raw    = v0 + B_ * N2_ * D_;                        // 9437184 floats (38 MB)

    k1_s0      <<<dim3(8, 32),  256, 0, stream>>>(x, W, s_part);
    k2_squash  <<<512,          256, 0, stream>>>(s_part, v0, 1.f / 128.f);
    k3a_raw    <<<dim3(16, 32), 256, 0, stream>>>(x, W, v0, raw);
    k3b_softmax<<<18432,        256, 0, stream>>>(raw);
    k3c_s1     <<<dim3(8, 32),  256, 0, stream>>>(x, W, raw, s_part);
    k2_squash  <<<512,          256, 0, stream>>>(s_part, out, 1.f);
}

// Round 2
// 282.431 us; speedup vs baseline: 1.4418x; 1.4418x over previous
//
#include <hip/hip_runtime.h>
#include <math.h>

// dims
#define B_   64
#define N1_  1152
#define P_   8
#define N2_  128
#define D_   16
#define ISPLIT 32
#define ICH  (N1_/ISPLIT)   // 36 i's per split

// ---------------------------------------------------------------------------
// K1: s0 partials.  s0p[split][b][n][d] = sum_{i in split, p} W[i,n,d,p]*x[b,i,p]
// block: 256 thr = (n 16) x (bgroup 8 -> 4 b each) x (dgroup 2 -> 8 d each)
// grid: (N2/16, ISPLIT, 2) = (8, 32, 2); z splits batch. 2 blocks/CU.
// W staging double-buffered: prefetch tile ii+1 into regs during compute of ii.
// ---------------------------------------------------------------------------
__global__ __launch_bounds__(256) void k1_s0(const float* __restrict__ x,
                                             const float* __restrict__ W,
                                             float* __restrict__ s0p)
{
    __shared__ float Wl[2][16 * 132];         // 2 x (16 n x (128+4 pad))
    const int tid = threadIdx.x;
    const int n0  = blockIdx.x * 16;
    const int isp = blockIdx.y;
    const int i0  = isp * ICH;
    const int nl  = tid & 15;
    const int bg  = (tid >> 4) & 7;
    const int dg  = tid >> 7;
    const int b0  = blockIdx.z * 32 + bg * 4;
    const int d0  = dg * 8;

    const int st0 = tid, st1 = tid + 256;     // float4 indices into 512-f4 tile
    const int nn0 = st0 >> 5, r0 = st0 & 31;
    const int nn1 = st1 >> 5, r1 = st1 & 31;

    float4 pf0, pf1;
    {
        const float4* Wg = (const float4*)(W + ((size_t)i0 * N2_ + n0) * (D_ * P_));
        pf0 = Wg[st0]; pf1 = Wg[st1];
        *(float4*)&Wl[0][nn0 * 132 + r0 * 4] = pf0;
        *(float4*)&Wl[0][nn1 * 132 + r1 * 4] = pf1;
    }

    float acc[4][8];
#pragma unroll
    for (int a = 0; a < 4; ++a)
#pragma unroll
        for (int c = 0; c < 8; ++c) acc[a][c] = 0.f;

    for (int ii = 0; ii < ICH; ++ii) {
        const int i = i0 + ii;
        if (ii + 1 < ICH) {                   // issue next tile's loads early
            const float4* Wg = (const float4*)(W + ((size_t)(i + 1) * N2_ + n0) * (D_ * P_));
            pf0 = Wg[st0]; pf1 = Wg[st1];
        }
        __syncthreads();                      // Wl[ii&1] ready for all waves
        const float* Wb = Wl[ii & 1];

        float xr[4][8];
#pragma unroll
        for (int bb = 0; bb < 4; ++bb) {
            const float* xp = x + ((size_t)(b0 + bb) * N1_ + i) * P_;
            float4 a0 = *(const float4*)xp;
            float4 a1 = *(const float4*)(xp + 4);
            xr[bb][0] = a0.x; xr[bb][1] = a0.y; xr[bb][2] = a0.z; xr[bb][3] = a0.w;
            xr[bb][4] = a1.x; xr[bb][5] = a1.y; xr[bb][6] = a1.z; xr[bb][7] = a1.w;
        }
#pragma unroll
        for (int dd = 0; dd < 8; ++dd) {
            const float* wp = &Wb[nl * 132 + (d0 + dd) * P_];
            float4 w0 = *(const float4*)wp;
            float4 w1 = *(const float4*)(wp + 4);
#pragma unroll
            for (int bb = 0; bb < 4; ++bb) {
                float t = w0.x * xr[bb][0] + w0.y * xr[bb][1]
                        + w0.z * xr[bb][2] + w0.w * xr[bb][3]
                        + w1.x * xr[bb][4] + w1.y * xr[bb][5]
                        + w1.z * xr[bb][6] + w1.w * xr[bb][7];
                acc[bb][dd] += t;
            }
        }
        if (ii + 1 < ICH) {                   // store prefetch into other buffer
            float* Wn = Wl[(ii + 1) & 1];
            *(float4*)&Wn[nn0 * 132 + r0 * 4] = pf0;
            *(float4*)&Wn[nn1 * 132 + r1 * 4] = pf1;
        }
    }
#pragma unroll
    for (int bb = 0; bb < 4; ++bb)
#pragma unroll
        for (int dd = 0; dd < 8; ++dd)
            s0p[(size_t)isp * (B_ * N2_ * D_) + (size_t)(b0 + bb) * (N2_ * D_)
                + (n0 + nl) * D_ + d0 + dd] = acc[bb][dd];
}

// ---------------------------------------------------------------------------
// K2/K4: reduce ISPLIT partials, scale, squash over d (16), write v.
// ---------------------------------------------------------------------------
__global__ __launch_bounds__(256) void k2_squash(const float* __restrict__ spart,
                                                 float* __restrict__ vout,
                                                 float scale)
{
    int idx = blockIdx.x * 256 + threadIdx.x;   // 0 .. 131071
    float s = 0.f;
    for (int sp = 0; sp < ISPLIT; ++sp)
        s += spart[(size_t)sp * (B_ * N2_ * D_) + idx];
    s *= scale;
    float sq = s * s;
    sq += __shfl_xor(sq, 1);
    sq += __shfl_xor(sq, 2);
    sq += __shfl_xor(sq, 4);
    sq += __shfl_xor(sq, 8);
    float norm = sqrtf(sq + 1.1920929e-7f);
    vout[idx] = (sq / (1.f + sq)) * (s / norm);
}

// ---------------------------------------------------------------------------
// K3a: raw[b][i][n] = sum_d v0[b,n,d] * (sum_p W[i,n,d,p]*x[b,i,p])
// block: 256 thr = (n 8) x (bgroup 16 -> 4 b each) x (ii 2); grid (16, 32).
// double-buffered W staging like k1.
// ---------------------------------------------------------------------------
__global__ __launch_bounds__(256) void k3a_raw(const float* __restrict__ x,
                                               const float* __restrict__ W,
                                               const float* __restrict__ v0,
                                               float* __restrict__ raw)
{
    __shared__ float Wl[2][2 * 8 * 132];        // 2 x ([ii][n][128+4])
    const int tid = threadIdx.x;
    const int n0  = blockIdx.x * 8;
    const int i0  = blockIdx.y * ICH;
    const int nl  = tid & 7;
    const int bgi = (tid >> 3) & 15;
    const int ii  = tid >> 7;
    const int b0  = bgi * 4;

    // staging decomposition for 512 float4 per tile (2 per thread)
    const int st0 = tid, st1 = tid + 256;
    const int iw0 = st0 >> 8, rem0 = st0 & 255, sn0 = rem0 >> 5, sr0 = rem0 & 31;
    const int iw1 = st1 >> 8, rem1 = st1 & 255, sn1 = rem1 >> 5, sr1 = rem1 & 31;

    float v0r[4][16];
#pragma unroll
    for (int bb = 0; bb < 4; ++bb) {
        const float4* vp = (const float4*)(v0 + (size_t)(b0 + bb) * (N2_ * D_)
                                           + (n0 + nl) * D_);
        float4 q0 = vp[0], q1 = vp[1], q2 = vp[2], q3 = vp[3];
        v0r[bb][0]  = q0.x; v0r[bb][1]  = q0.y; v0r[bb][2]  = q0.z; v0r[bb][3]  = q0.w;
        v0r[bb][4]  = q1.x; v0r[bb][5]  = q1.y; v0r[bb][6]  = q1.z; v0r[bb][7]  = q1.w;
        v0r[bb][8]  = q2.x; v0r[bb][9]  = q2.y; v0r[bb][10] = q2.z; v0r[bb][11] = q2.w;
        v0r[bb][12] = q3.x; v0r[bb][13] = q3.y; v0r[bb][14] = q3.z; v0r[bb][15] = q3.w;
    }

    float4 pf0, pf1;
    {
        pf0 = *(const float4*)(W + ((size_t)(i0 + iw0) * N2_ + n0 + sn0) * (D_ * P_) + sr0 * 4);
        pf1 = *(const float4*)(W + ((size_t)(i0 + iw1) * N2_ + n0 + sn1) * (D_ * P_) + sr1 * 4);
        *(float4*)&Wl[0][(iw0 * 8 + sn0) * 132 + sr0 * 4] = pf0;
        *(float4*)&Wl[0][(iw1 * 8 + sn1) * 132 + sr1 * 4] = pf1;
    }

    const int NT = ICH / 2;                    // 18 tiles of 2 i's
    for (int s = 0; s < NT; ++s) {
        if (s + 1 < NT) {
            const int ib = i0 + 2 * (s + 1);
            pf0 = *(const float4*)(W + ((size_t)(ib + iw0) * N2_ + n0 + sn0) * (D_ * P_) + sr0 * 4);
            pf1 = *(const float4*)(W + ((size_t)(ib + iw1) * N2_ + n0 + sn1) * (D_ * P_) + sr1 * 4);
        }
        __syncthreads();
        const float* Wb = Wl[s & 1];

        const int i = i0 + 2 * s + ii;
        float xr[4][8];
#pragma unroll
        for (int bb = 0; bb < 4; ++bb) {
            const float* xp = x + ((size_t)(b0 + bb) * N1_ + i) * P_;
            float4 a0 = *(const float4*)xp;
            float4 a1 = *(const float4*)(xp + 4);
            xr[bb][0] = a0.x; xr[bb][1] = a0.y; xr[bb][2] = a0.z; xr[bb][3] = a0.w;
            xr[bb][4] = a1.x; xr[bb][5] = a1.y; xr[bb][6] = a1.z; xr[bb][7] = a1.w;
        }
        float rawp[4] = {0.f, 0.f, 0.f, 0.f};
#pragma unroll
        for (int d = 0; d < 16; ++d) {
            const float* wp = &Wb[(ii * 8 + nl) * 132 + d * P_];
            float4 w0 = *(const float4*)wp;
            float4 w1 = *(const float4*)(wp + 4);
#pragma unroll
            for (int bb = 0; bb < 4; ++bb) {
                float t = w0.x * xr[bb][0] + w0.y * xr[bb][1]
                        + w0.z * xr[bb][2] + w0.w * xr[bb][3]
                        + w1.x * xr[bb][4] + w1.y * xr[bb][5]
                        + w1.z * xr[bb][6] + w1.w * xr[bb][7];
                rawp[bb] += t * v0r[bb][d];
            }
        }
#pragma unroll
        for (int bb = 0; bb < 4; ++bb)
            raw[(size_t)(b0 + bb) * (N1_ * N2_) + (size_t)i * N2_ + n0 + nl] = rawp[bb];

        if (s + 1 < NT) {
            float* Wn = Wl[(s + 1) & 1];
            *(float4*)&Wn[(iw0 * 8 + sn0) * 132 + sr0 * 4] = pf0;
            *(float4*)&Wn[(iw1 * 8 + sn1) * 132 + sr1 * 4] = pf1;
        }
    }
}

// ---------------------------------------------------------------------------
// K3b: in-place softmax over n (128) per (b,i) row. one wave per row.
// ---------------------------------------------------------------------------
__global__ __launch_bounds__(256) void k3b_softmax(float* __restrict__ raw)
{
    int row  = blockIdx.x * 4 + (threadIdx.x >> 6);   // 0 .. 73727
    int lane = threadIdx.x & 63;
    float* rp = raw + (size_t)row * N2_;
    float a = rp[lane], b = rp[lane + 64];
    float m = fmaxf(a, b);
#pragma unroll
    for (int off = 32; off >= 1; off >>= 1) m = fmaxf(m, __shfl_xor(m, off));
    float e0 = __expf(a - m), e1 = __expf(b - m);
    float ssum = e0 + e1;
#pragma unroll
    for (int off = 32; off >= 1; off >>= 1) ssum += __shfl_xor(ssum, off);
    float inv = 1.f / ssum;
    rp[lane] = e0 * inv;
    rp[lane + 64] = e1 * inv;
}

// ---------------------------------------------------------------------------
// K3c: s1 partials.  s1p[split][b][n][d] = sum_{i in split} c[b,i,n]*pred[b,i,n,d]
// identical pipeline to K1 plus the c weight.
// ---------------------------------------------------------------------------
__global__ __launch_bounds__(256) void k3c_s1(const float* __restrict__ x,
                                              const float* __restrict__ W,
                                              const float* __restrict__ cmat,
                                              float* __restrict__ s1p)
{
    __shared__ float Wl[2][16 * 132];
    const int tid = threadIdx.x;
    const int n0  = blockIdx.x * 16;
    const int isp = blockIdx.y;
    const int i0  = isp * ICH;
    const int nl  = tid & 15;
    const int bg  = (tid >> 4) & 7;
    const int dg  = tid >> 7;
    const int b0  = blockIdx.z * 32 + bg * 4;
    const int d0  = dg * 8;

    const int st0 = tid, st1 = tid + 256;
    const int nn0 = st0 >> 5, r0 = st0 & 31;
    const int nn1 = st1 >> 5, r1 = st1 & 31;

    float4 pf0, pf1;
    {
        const float4* Wg = (const float4*)(W + ((size_t)i0 * N2_ + n0) * (D_ * P_));
        pf0 = Wg[st0]; pf1 = Wg[st1];
        *(float4*)&Wl[0][nn0 * 132 + r0 * 4] = pf0;
        *(float4*)&Wl[0][nn1 * 132 + r1 * 4] = pf1;
    }

    float acc[4][8];
#pragma unroll
    for (int a = 0; a < 4; ++a)
#pragma unroll
        for (int c = 0; c < 8; ++c) acc[a][c] = 0.f;

    for (int ii = 0; ii < ICH; ++ii) {
        const int i = i0 + ii;
        if (ii + 1 < ICH) {
            const float4* Wg = (const float4*)(W + ((size_t)(i + 1) * N2_ + n0) * (D_ * P_));
            pf0 = Wg[st0]; pf1 = Wg[st1];
        }
        __syncthreads();
        const float* Wb = Wl[ii & 1];

        float xr[4][8];
        float cr[4];
#pragma unroll
        for (int bb = 0; bb < 4; ++bb) {
            const float* xp = x + ((size_t)(b0 + bb) * N1_ + i) * P_;
            float4 a0 = *(const float4*)xp;
            float4 a1 = *(const float4*)(xp + 4);
            xr[bb][0] = a0.x; xr[bb][1] = a0.y; xr[bb][2] = a0.z; xr[bb][3] = a0.w;
            xr[bb][4] = a1.x; xr[bb][5] = a1.y; xr[bb][6] = a1.z; xr[bb][7] = a1.w;
            cr[bb] = cmat[(size_t)(b0 + bb) * (N1_ * N2_) + (size_t)i * N2_ + n0 + nl];
        }
#pragma unroll
        for (int dd = 0; dd < 8; ++dd) {
            const float* wp = &Wb[nl * 132 + (d0 + dd) * P_];
            float4 w0 = *(const float4*)wp;
            float4 w1 = *(const float4*)(wp + 4);
#pragma unroll
            for (int bb = 0; bb < 4; ++bb) {
                float t = w0.x * xr[bb][0] + w0.y * xr[bb][1]
                        + w0.z * xr[bb][2] + w0.w * xr[bb][3]
                        + w1.x * xr[bb][4] + w1.y * xr[bb][5]
                        + w1.z * xr[bb][6] + w1.w * xr[bb][7];
                acc[bb][dd] += cr[bb] * t;
            }
        }
        if (ii + 1 < ICH) {
            float* Wn = Wl[(ii + 1) & 1];
            *(float4*)&Wn[nn0 * 132 + r0 * 4] = pf0;
            *(float4*)&Wn[nn1 * 132 + r1 * 4] = pf1;
        }
    }
#pragma unroll
    for (int bb = 0; bb < 4; ++bb)
#pragma unroll
        for (int dd = 0; dd < 8; ++dd)
            s1p[(size_t)isp * (B_ * N2_ * D_) + (size_t)(b0 + bb) * (N2_ * D_)
                + (n0 + nl) * D_ + d0 + dd] = acc[bb][dd];
}

// ---------------------------------------------------------------------------
extern "C" void kernel_launch(void* const* d_in, const int* in_sizes, int n_in,
                              void* d_out, int out_size, void* d_ws, size_t ws_size,
                              hipStream_t stream)
{
    const float* x = (const float*)d_in[0];   // [64,1152,8]
    const float* W = (const float*)d_in[1];   // [1152,128,16,8]
    float* out = (float*)d_out;               // [64,128,16]

    float* s_part = (float*)d_ws;                              // 32*131072 floats (16 MB)
    float* v0     = s_part + (size_t)ISPLIT * B_ * N2_ * D_;   // 131072 floats
    float* raw    = v0 + B_ * N2_ * D_;                        // 9437184 floats (38 MB)

    k1_s0      <<<dim3(8, 32, 2), 256, 0, stream>>>(x, W, s_part);
    k2_squash  <<<512,            256, 0, stream>>>(s_part, v0, 1.f / 128.f);
    k3a_raw    <<<dim3(16, 32),   256, 0, stream>>>(x, W, v0, raw);
    k3b_softmax<<<18432,          256, 0, stream>>>(raw);
    k3c_s1     <<<dim3(8, 32, 2), 256, 0, stream>>>(x, W, raw, s_part);
    k2_squash  <<<512,            256, 0, stream>>>(s_part, out, 1.f);
}